// Round 5
// baseline (1246.719 us; speedup 1.0000x reference)
//
#include <hip/hip_runtime.h>
#include <hip/hip_fp16.h>

#define F_IN   128
#define F_HID  16
#define NPB    2048          // nodes per bucket
#define NPB_SH 11
#define SRC_BITS 19
#define SRC_MASK 0x7FFFFu
#define ACC_STRIDE 16        // fp32 feats per node in LDS acc (128 KB total)

// ---------------- bucket histogram (dst >> 11) ----------------
__global__ __launch_bounds__(256) void k_hist1(const int* __restrict__ dst,
                                               unsigned* __restrict__ bcnt, int E) {
    __shared__ unsigned h[256];
    h[threadIdx.x] = 0;
    __syncthreads();
    for (int i = blockIdx.x * 256 + threadIdx.x; i < E; i += gridDim.x * 256)
        atomicAdd(&h[((unsigned)dst[i]) >> NPB_SH], 1u);
    __syncthreads();
    if (h[threadIdx.x]) atomicAdd(&bcnt[threadIdx.x], h[threadIdx.x]);
}

// ---------------- scan 256 bucket counts ----------------
__global__ __launch_bounds__(256) void k_scanb(const unsigned* __restrict__ bcnt,
                                               unsigned* __restrict__ bbase,
                                               unsigned* __restrict__ bfill) {
    __shared__ unsigned s[256];
    unsigned v = bcnt[threadIdx.x];
    s[threadIdx.x] = v;
    __syncthreads();
    for (int off = 1; off < 256; off <<= 1) {
        unsigned t = (threadIdx.x >= (unsigned)off) ? s[threadIdx.x - off] : 0u;
        __syncthreads();
        s[threadIdx.x] += t;
        __syncthreads();
    }
    unsigned incl = s[threadIdx.x];
    bbase[threadIdx.x + 1] = incl;
    bfill[threadIdx.x] = incl - v;    // exclusive
    if (threadIdx.x == 0) bbase[0] = 0;
}

// ---------------- bin edges into buckets (packed (ldst<<19)|src) ----------------
__global__ __launch_bounds__(1024) void k_bin(const int* __restrict__ src,
                                              const int* __restrict__ dst,
                                              unsigned* __restrict__ bfill,
                                              unsigned* __restrict__ binned, int E) {
    __shared__ unsigned hist[256], fill2[256], runbase[256];
    if (threadIdx.x < 256) { hist[threadIdx.x] = 0; fill2[threadIdx.x] = 0; }
    __syncthreads();
    unsigned val[8]; unsigned bkt[8]; bool ok[8];
    int base = blockIdx.x * 8192;
#pragma unroll
    for (int k = 0; k < 8; k++) {
        int e = base + k * 1024 + threadIdx.x;
        ok[k] = e < E;
        if (ok[k]) {
            unsigned d = (unsigned)dst[e];
            unsigned s = (unsigned)src[e];
            bkt[k] = d >> NPB_SH;
            val[k] = ((d & (NPB - 1)) << SRC_BITS) | s;
            atomicAdd(&hist[bkt[k]], 1u);
        }
    }
    __syncthreads();
    if (threadIdx.x < 256 && hist[threadIdx.x])
        runbase[threadIdx.x] = atomicAdd(&bfill[threadIdx.x], hist[threadIdx.x]);
    __syncthreads();
#pragma unroll
    for (int k = 0; k < 8; k++) {
        if (ok[k]) {
            unsigned pos = runbase[bkt[k]] + atomicAdd(&fill2[bkt[k]], 1u);
            binned[pos] = val[k];
        }
    }
}

// ---------------- per-bucket degree -> dinv ----------------
__global__ __launch_bounds__(1024) void k_deg(const unsigned* __restrict__ binned,
                                              const unsigned* __restrict__ bbase,
                                              float* __restrict__ dinv, int n) {
    __shared__ unsigned cnt[NPB];
    int b = blockIdx.x;
    unsigned estart = bbase[b], eend = bbase[b + 1];
    cnt[threadIdx.x] = 0; cnt[threadIdx.x + 1024] = 0;
    __syncthreads();
    for (unsigned i = estart + threadIdx.x; i < eend; i += 1024)
        atomicAdd(&cnt[binned[i] >> SRC_BITS], 1u);
    __syncthreads();
    int g0 = b * NPB + threadIdx.x;
    int g1 = g0 + 1024;
    if (g0 < n) dinv[g0] = rsqrtf((float)cnt[threadIdx.x] + 1.0f);
    if (g1 < n) dinv[g1] = rsqrtf((float)cnt[threadIdx.x + 1024] + 1.0f);
}

// ---------------- h1' = fp16( dinv .* (x @ W1) )  (LDS-staged + reg dbuf) ----------------
#define KC 32
#define XS_STRIDE 36
__global__ __launch_bounds__(256) void k_gemm1(const float* __restrict__ x,
                                               const float* __restrict__ W1,
                                               const float* __restrict__ dinv,
                                               __half* __restrict__ h1, int n) {
    __shared__ float Ws[F_IN * F_HID];          // 8 KB
    __shared__ float xs[256 * XS_STRIDE];       // 36 KB
    for (int i = threadIdx.x; i < F_IN * F_HID; i += 256) Ws[i] = W1[i];
    int t = threadIdx.x;
    int node0 = blockIdx.x * 256;
    bool active = (node0 + t) < n;
    float acc[F_HID];
#pragma unroll
    for (int c = 0; c < F_HID; c++) acc[c] = 0.f;

    float4 rbuf[8];
    auto loadc = [&](int c) {
#pragma unroll
        for (int i2 = 0; i2 < 8; i2++) {
            int f = t + i2 * 256;                // float4 index 0..2047
            int r = f >> 3;                      // staged row 0..255
            int j4 = f & 7;                      // float4 within chunk
            int gn = node0 + r;
            rbuf[i2] = (gn < n)
                ? *(const float4*)(x + (size_t)gn * F_IN + c * KC + j4 * 4)
                : make_float4(0.f, 0.f, 0.f, 0.f);
        }
    };
    loadc(0);
    for (int c = 0; c < F_IN / KC; c++) {       // 4 K-chunks
        __syncthreads();                         // xs free to overwrite (orders Ws on c==0)
#pragma unroll
        for (int i2 = 0; i2 < 8; i2++) {
            int f = t + i2 * 256;
            int r = f >> 3;
            int j4 = f & 7;
            *(float4*)(xs + r * XS_STRIDE + j4 * 4) = rbuf[i2];
        }
        __syncthreads();                         // xs ready
        if (c + 1 < F_IN / KC) loadc(c + 1);     // in-flight during compute below
        if (active) {
#pragma unroll
            for (int j4 = 0; j4 < 8; j4++) {
                float4 p = *(const float4*)(xs + t * XS_STRIDE + j4 * 4);
                int kk = c * KC + j4 * 4;
                const float* w0 = &Ws[(kk + 0) * F_HID];
                const float* w1 = &Ws[(kk + 1) * F_HID];
                const float* w2 = &Ws[(kk + 2) * F_HID];
                const float* w3 = &Ws[(kk + 3) * F_HID];
#pragma unroll
                for (int cc = 0; cc < F_HID; cc++)
                    acc[cc] += p.x * w0[cc] + p.y * w1[cc] + p.z * w2[cc] + p.w * w3[cc];
            }
        }
    }
    if (!active) return;
    float di = dinv[node0 + t];
    __half2 hv[8];
#pragma unroll
    for (int q = 0; q < 8; q++)
        hv[q] = __floats2half2_rn(acc[2 * q] * di, acc[2 * q + 1] * di);
    uint4* out = (uint4*)(h1 + (size_t)(node0 + t) * F_HID);   // 32B/node
    out[0] = *(uint4*)&hv[0];
    out[1] = *(uint4*)&hv[4];
}

// ---- layer-1 fused aggregate over binned (no CSR): LDS acc[2048][16] fp32 ----
// unsafeAtomicAdd -> hardware ds_add_f32 (no return, fire-and-forget): no
// lgkmcnt round-trip in the loop, unlike default fp32 atomicAdd which emits
// a CAS loop (~275 cy serial LDS chain per call site -- the R4 regression).
__global__ __launch_bounds__(1024) void k_aggf1(const unsigned* __restrict__ binned,
                                                const unsigned* __restrict__ bbase,
                                                const float* __restrict__ dinv,
                                                const __half* __restrict__ h1,
                                                const float* __restrict__ b1,
                                                const float* __restrict__ W2,
                                                float2* __restrict__ h2, int n) {
    __shared__ float acc[NPB * ACC_STRIDE];     // 128 KB
    int b = blockIdx.x;
    unsigned estart = bbase[b], eend = bbase[b + 1];
    float4* az = (float4*)acc;
    for (int i = threadIdx.x; i < NPB * ACC_STRIDE / 4; i += 1024)
        az[i] = make_float4(0.f, 0.f, 0.f, 0.f);
    __syncthreads();

    int lane = threadIdx.x & 15;
    int grp  = threadIdx.x >> 4;                // 0..63
    unsigned ecount = eend - estart;
    unsigned chunk = (ecount + 63) >> 6;
    unsigned gs = estart + (unsigned)grp * chunk;
    unsigned ge = gs + chunk;
    if (gs > eend) gs = eend;
    if (ge > eend) ge = eend;
    unsigned i = gs;
    for (; i + 8 <= ge; i += 8) {
        unsigned v0 = binned[i + 0], v1 = binned[i + 1], v2 = binned[i + 2], v3 = binned[i + 3];
        unsigned v4 = binned[i + 4], v5 = binned[i + 5], v6 = binned[i + 6], v7 = binned[i + 7];
        float f0 = __half2float(h1[(size_t)(v0 & SRC_MASK) * F_HID + lane]);
        float f1 = __half2float(h1[(size_t)(v1 & SRC_MASK) * F_HID + lane]);
        float f2 = __half2float(h1[(size_t)(v2 & SRC_MASK) * F_HID + lane]);
        float f3 = __half2float(h1[(size_t)(v3 & SRC_MASK) * F_HID + lane]);
        float f4 = __half2float(h1[(size_t)(v4 & SRC_MASK) * F_HID + lane]);
        float f5 = __half2float(h1[(size_t)(v5 & SRC_MASK) * F_HID + lane]);
        float f6 = __half2float(h1[(size_t)(v6 & SRC_MASK) * F_HID + lane]);
        float f7 = __half2float(h1[(size_t)(v7 & SRC_MASK) * F_HID + lane]);
        unsafeAtomicAdd(&acc[(v0 >> SRC_BITS) * ACC_STRIDE + lane], f0);
        unsafeAtomicAdd(&acc[(v1 >> SRC_BITS) * ACC_STRIDE + lane], f1);
        unsafeAtomicAdd(&acc[(v2 >> SRC_BITS) * ACC_STRIDE + lane], f2);
        unsafeAtomicAdd(&acc[(v3 >> SRC_BITS) * ACC_STRIDE + lane], f3);
        unsafeAtomicAdd(&acc[(v4 >> SRC_BITS) * ACC_STRIDE + lane], f4);
        unsafeAtomicAdd(&acc[(v5 >> SRC_BITS) * ACC_STRIDE + lane], f5);
        unsafeAtomicAdd(&acc[(v6 >> SRC_BITS) * ACC_STRIDE + lane], f6);
        unsafeAtomicAdd(&acc[(v7 >> SRC_BITS) * ACC_STRIDE + lane], f7);
    }
    for (; i < ge; ++i) {
        unsigned v = binned[i];
        float f = __half2float(h1[(size_t)(v & SRC_MASK) * F_HID + lane]);
        unsafeAtomicAdd(&acc[(v >> SRC_BITS) * ACC_STRIDE + lane], f);
    }
    __syncthreads();

    // epilogue: 2 nodes per thread, coalesced over node index
#pragma unroll
    for (int q = 0; q < 2; q++) {
        int ld = threadIdx.x + q * 1024;
        int g = b * NPB + ld;
        if (g < n) {
            float di = dinv[g];
            const __half* hs = h1 + (size_t)g * F_HID;
            float c0 = 0.f, c1 = 0.f;
#pragma unroll
            for (int f = 0; f < F_HID; f++) {
                float s = acc[ld * ACC_STRIDE + f] + __half2float(hs[f]);
                s = s * di + b1[f];
                float v = fmaxf(s, 0.f);
                c0 += v * W2[f * 2 + 0];
                c1 += v * W2[f * 2 + 1];
            }
            h2[g] = make_float2(c0 * di, c1 * di);   // h2' = dinv * h2
        }
    }
}

// ---- layer-2 fused aggregate over binned: LDS acc[2048][2] + log_softmax ----
__global__ __launch_bounds__(1024) void k_aggf2(const unsigned* __restrict__ binned,
                                                const unsigned* __restrict__ bbase,
                                                const float* __restrict__ dinv,
                                                const float2* __restrict__ h2,
                                                const float* __restrict__ b2,
                                                float2* __restrict__ out, int n) {
    __shared__ float acc[NPB * 2];              // 16 KB
    int b = blockIdx.x;
    unsigned estart = bbase[b], eend = bbase[b + 1];
    float4* az = (float4*)acc;
    for (int i = threadIdx.x; i < NPB * 2 / 4; i += 1024)
        az[i] = make_float4(0.f, 0.f, 0.f, 0.f);
    __syncthreads();

    unsigned i = estart + threadIdx.x;
    for (; i + 3072 < eend; i += 4096) {
        unsigned v0 = binned[i], v1 = binned[i + 1024], v2 = binned[i + 2048], v3 = binned[i + 3072];
        float2 g0 = h2[v0 & SRC_MASK];
        float2 g1 = h2[v1 & SRC_MASK];
        float2 g2 = h2[v2 & SRC_MASK];
        float2 g3 = h2[v3 & SRC_MASK];
        unsafeAtomicAdd(&acc[(v0 >> SRC_BITS) * 2 + 0], g0.x);
        unsafeAtomicAdd(&acc[(v0 >> SRC_BITS) * 2 + 1], g0.y);
        unsafeAtomicAdd(&acc[(v1 >> SRC_BITS) * 2 + 0], g1.x);
        unsafeAtomicAdd(&acc[(v1 >> SRC_BITS) * 2 + 1], g1.y);
        unsafeAtomicAdd(&acc[(v2 >> SRC_BITS) * 2 + 0], g2.x);
        unsafeAtomicAdd(&acc[(v2 >> SRC_BITS) * 2 + 1], g2.y);
        unsafeAtomicAdd(&acc[(v3 >> SRC_BITS) * 2 + 0], g3.x);
        unsafeAtomicAdd(&acc[(v3 >> SRC_BITS) * 2 + 1], g3.y);
    }
    for (; i < eend; i += 1024) {
        unsigned v = binned[i];
        float2 gv = h2[v & SRC_MASK];
        unsafeAtomicAdd(&acc[(v >> SRC_BITS) * 2 + 0], gv.x);
        unsafeAtomicAdd(&acc[(v >> SRC_BITS) * 2 + 1], gv.y);
    }
    __syncthreads();

#pragma unroll
    for (int q = 0; q < 2; q++) {
        int ld = threadIdx.x + q * 1024;
        int g = b * NPB + ld;
        if (g < n) {
            float di = dinv[g];
            float2 hs = h2[g];
            float v0 = (acc[ld * 2 + 0] + hs.x) * di + b2[0];
            float v1 = (acc[ld * 2 + 1] + hs.y) * di + b2[1];
            float m = fmaxf(v0, v1);
            float lse = m + log1pf(expf(fminf(v0, v1) - m));
            out[g] = make_float2(v0 - lse, v1 - lse);
        }
    }
}

extern "C" void kernel_launch(void* const* d_in, const int* in_sizes, int n_in,
                              void* d_out, int out_size, void* d_ws, size_t ws_size,
                              hipStream_t stream) {
    const float* x  = (const float*)d_in[0];
    const int*   ei = (const int*)d_in[1];
    const float* W1 = (const float*)d_in[2];
    const float* b1 = (const float*)d_in[3];
    const float* W2 = (const float*)d_in[4];
    const float* b2 = (const float*)d_in[5];

    int n = in_sizes[0] / F_IN;   // 500000
    int E = in_sizes[1] / 2;      // 8000000
    const int* src = ei;
    const int* dst = ei + E;
    int B = (n + NPB - 1) / NPB;  // 245 buckets

    // workspace layout (binned persists through aggf2; h1 separate)
    char* ws = (char*)d_ws;
    size_t off = 0;
    auto alloc = [&](size_t bytes) { char* p = ws + off; off = (off + bytes + 63) & ~size_t(63); return p; };
    float*    dinv    = (float*)alloc(4 * (size_t)n);
    unsigned* bcnt    = (unsigned*)alloc(1024);
    unsigned* bbase   = (unsigned*)alloc(1028);
    unsigned* bfill   = (unsigned*)alloc(1024);
    unsigned* binned  = (unsigned*)alloc(4 * (size_t)E);   // 32 MB
    __half*   h1      = (__half*)alloc(2 * (size_t)n * F_HID);  // 16 MB
    float2*   h2      = (float2*)alloc(8 * (size_t)n);     // 4 MB

    int bN = (n + 255) / 256;
    int bBIN = (E + 8191) / 8192;

    hipMemsetAsync(bcnt, 0, 1024, stream);
    k_hist1 <<<1024, 256, 0, stream>>>(dst, bcnt, E);
    k_scanb <<<1, 256, 0, stream>>>(bcnt, bbase, bfill);
    k_bin   <<<bBIN, 1024, 0, stream>>>(src, dst, bfill, binned, E);
    k_deg   <<<B, 1024, 0, stream>>>(binned, bbase, dinv, n);
    k_gemm1 <<<bN, 256, 0, stream>>>(x, W1, dinv, h1, n);
    k_aggf1 <<<B, 1024, 0, stream>>>(binned, bbase, dinv, h1, b1, W2, h2, n);
    k_aggf2 <<<B, 1024, 0, stream>>>(binned, bbase, dinv, h2, b2, (float2*)d_out, n);
}

// Round 6
// 744.022 us; speedup vs baseline: 1.6756x; 1.6756x over previous
//
#include <hip/hip_runtime.h>
#include <hip/hip_fp16.h>

#define F_IN   128
#define F_HID  16
#define NPB    2048          // nodes per bucket
#define NPB_SH 11
#define SRC_BITS 19
#define SRC_MASK 0x7FFFFu

// ---------------- bucket histogram (dst >> 11) ----------------
__global__ __launch_bounds__(256) void k_hist1(const int* __restrict__ dst,
                                               unsigned* __restrict__ bcnt, int E) {
    __shared__ unsigned h[256];
    h[threadIdx.x] = 0;
    __syncthreads();
    for (int i = blockIdx.x * 256 + threadIdx.x; i < E; i += gridDim.x * 256)
        atomicAdd(&h[((unsigned)dst[i]) >> NPB_SH], 1u);
    __syncthreads();
    if (h[threadIdx.x]) atomicAdd(&bcnt[threadIdx.x], h[threadIdx.x]);
}

// ---------------- scan 256 bucket counts ----------------
__global__ __launch_bounds__(256) void k_scanb(const unsigned* __restrict__ bcnt,
                                               unsigned* __restrict__ bbase,
                                               unsigned* __restrict__ bfill,
                                               unsigned* __restrict__ row_ptr,
                                               int n, int E) {
    __shared__ unsigned s[256];
    unsigned v = bcnt[threadIdx.x];
    s[threadIdx.x] = v;
    __syncthreads();
    for (int off = 1; off < 256; off <<= 1) {
        unsigned t = (threadIdx.x >= (unsigned)off) ? s[threadIdx.x - off] : 0u;
        __syncthreads();
        s[threadIdx.x] += t;
        __syncthreads();
    }
    unsigned incl = s[threadIdx.x];
    bbase[threadIdx.x + 1] = incl;
    bfill[threadIdx.x] = incl - v;    // exclusive
    if (threadIdx.x == 0) { bbase[0] = 0; row_ptr[n] = (unsigned)E; }
}

// ---------------- bin edges into buckets (packed (ldst<<19)|src) ----------------
__global__ __launch_bounds__(1024) void k_bin(const int* __restrict__ src,
                                              const int* __restrict__ dst,
                                              unsigned* __restrict__ bfill,
                                              unsigned* __restrict__ binned, int E) {
    __shared__ unsigned hist[256], fill2[256], runbase[256];
    if (threadIdx.x < 256) { hist[threadIdx.x] = 0; fill2[threadIdx.x] = 0; }
    __syncthreads();
    unsigned val[8]; unsigned bkt[8]; bool ok[8];
    int base = blockIdx.x * 8192;
#pragma unroll
    for (int k = 0; k < 8; k++) {
        int e = base + k * 1024 + threadIdx.x;
        ok[k] = e < E;
        if (ok[k]) {
            unsigned d = (unsigned)dst[e];
            unsigned s = (unsigned)src[e];
            bkt[k] = d >> NPB_SH;
            val[k] = ((d & (NPB - 1)) << SRC_BITS) | s;
            atomicAdd(&hist[bkt[k]], 1u);
        }
    }
    __syncthreads();
    if (threadIdx.x < 256 && hist[threadIdx.x])
        runbase[threadIdx.x] = atomicAdd(&bfill[threadIdx.x], hist[threadIdx.x]);
    __syncthreads();
#pragma unroll
    for (int k = 0; k < 8; k++) {
        if (ok[k]) {
            unsigned pos = runbase[bkt[k]] + atomicAdd(&fill2[bkt[k]], 1u);
            binned[pos] = val[k];
        }
    }
}

// ---- per-bucket: node histogram -> row_ptr, dinv, place adj (LDS atomics only) ----
__global__ __launch_bounds__(1024) void k_bucket(const unsigned* __restrict__ binned,
                                                 const unsigned* __restrict__ bbase,
                                                 int* __restrict__ adj,
                                                 unsigned* __restrict__ row_ptr,
                                                 float* __restrict__ dinv,
                                                 int n) {
    __shared__ unsigned cnt[NPB];
    __shared__ unsigned base[NPB];
    __shared__ unsigned pairs[1024];
    int b = blockIdx.x;
    unsigned estart = bbase[b], eend = bbase[b + 1];
    unsigned ecount = eend - estart;
    int nb_base = b * NPB;
    cnt[threadIdx.x] = 0; cnt[threadIdx.x + 1024] = 0;
    __syncthreads();
    for (unsigned i = threadIdx.x; i < ecount; i += 1024)
        atomicAdd(&cnt[binned[estart + i] >> SRC_BITS], 1u);
    __syncthreads();
    // scan 2048 counters: pair-sum + Hillis-Steele over 1024
    unsigned c0 = cnt[2 * threadIdx.x], c1 = cnt[2 * threadIdx.x + 1];
    pairs[threadIdx.x] = c0 + c1;
    __syncthreads();
    for (int off = 1; off < 1024; off <<= 1) {
        unsigned t = (threadIdx.x >= (unsigned)off) ? pairs[threadIdx.x - off] : 0u;
        __syncthreads();
        pairs[threadIdx.x] += t;
        __syncthreads();
    }
    unsigned ip = pairs[threadIdx.x];
    unsigned e0 = ip - c0 - c1;         // exclusive offset of node 2t
    unsigned e1 = ip - c1;              // exclusive offset of node 2t+1
    base[2 * threadIdx.x] = e0;
    base[2 * threadIdx.x + 1] = e1;
    int g0 = nb_base + 2 * threadIdx.x, g1 = g0 + 1;
    if (g0 < n) { row_ptr[g0] = estart + e0; dinv[g0] = rsqrtf((float)c0 + 1.0f); }
    if (g1 < n) { row_ptr[g1] = estart + e1; dinv[g1] = rsqrtf((float)c1 + 1.0f); }
    __syncthreads();
    cnt[threadIdx.x] = 0; cnt[threadIdx.x + 1024] = 0;   // reuse as fill
    __syncthreads();
    for (unsigned i = threadIdx.x; i < ecount; i += 1024) {
        unsigned v = binned[estart + i];
        unsigned ldst = v >> SRC_BITS;
        unsigned pos = base[ldst] + atomicAdd(&cnt[ldst], 1u);
        adj[estart + pos] = (int)(v & SRC_MASK);
    }
}

// ---------------- h1' = fp16( dinv .* (x @ W1) )  (LDS-staged + reg dbuf) ----------------
#define KC 32
#define XS_STRIDE 36
__global__ __launch_bounds__(256) void k_gemm1(const float* __restrict__ x,
                                               const float* __restrict__ W1,
                                               const float* __restrict__ dinv,
                                               __half* __restrict__ h1, int n) {
    __shared__ float Ws[F_IN * F_HID];          // 8 KB
    __shared__ float xs[256 * XS_STRIDE];       // 36 KB
    for (int i = threadIdx.x; i < F_IN * F_HID; i += 256) Ws[i] = W1[i];
    int t = threadIdx.x;
    int node0 = blockIdx.x * 256;
    bool active = (node0 + t) < n;
    float acc[F_HID];
#pragma unroll
    for (int c = 0; c < F_HID; c++) acc[c] = 0.f;

    float4 rbuf[8];
    auto loadc = [&](int c) {
#pragma unroll
        for (int i2 = 0; i2 < 8; i2++) {
            int f = t + i2 * 256;                // float4 index 0..2047
            int r = f >> 3;                      // staged row 0..255
            int j4 = f & 7;                      // float4 within chunk
            int gn = node0 + r;
            rbuf[i2] = (gn < n)
                ? *(const float4*)(x + (size_t)gn * F_IN + c * KC + j4 * 4)
                : make_float4(0.f, 0.f, 0.f, 0.f);
        }
    };
    loadc(0);
    for (int c = 0; c < F_IN / KC; c++) {       // 4 K-chunks
        __syncthreads();                         // xs free to overwrite (orders Ws on c==0)
#pragma unroll
        for (int i2 = 0; i2 < 8; i2++) {
            int f = t + i2 * 256;
            int r = f >> 3;
            int j4 = f & 7;
            *(float4*)(xs + r * XS_STRIDE + j4 * 4) = rbuf[i2];
        }
        __syncthreads();                         // xs ready
        if (c + 1 < F_IN / KC) loadc(c + 1);     // in-flight during compute below
        if (active) {
#pragma unroll
            for (int j4 = 0; j4 < 8; j4++) {
                float4 p = *(const float4*)(xs + t * XS_STRIDE + j4 * 4);
                int kk = c * KC + j4 * 4;
                const float* w0 = &Ws[(kk + 0) * F_HID];
                const float* w1 = &Ws[(kk + 1) * F_HID];
                const float* w2 = &Ws[(kk + 2) * F_HID];
                const float* w3 = &Ws[(kk + 3) * F_HID];
#pragma unroll
                for (int cc = 0; cc < F_HID; cc++)
                    acc[cc] += p.x * w0[cc] + p.y * w1[cc] + p.z * w2[cc] + p.w * w3[cc];
            }
        }
    }
    if (!active) return;
    float di = dinv[node0 + t];
    __half2 hv[8];
#pragma unroll
    for (int q = 0; q < 8; q++)
        hv[q] = __floats2half2_rn(acc[2 * q] * di, acc[2 * q + 1] * di);
    uint4* out = (uint4*)(h1 + (size_t)(node0 + t) * F_HID);   // 32B/node
    out[0] = *(uint4*)&hv[0];
    out[1] = *(uint4*)&hv[4];
}

// ---- layer-1 aggregate + self-loop + bias + ReLU + GEMM2 -> h2' (fp16) ----
// h1 is fp16 and pre-scaled by dinv: per edge only adj + a 32B row gather.
// 8-wide unroll keeps 8 independent gathers in flight per 16-lane group.
__global__ __launch_bounds__(256) void k_agg1(const int* __restrict__ adj,
                                              const unsigned* __restrict__ row_ptr,
                                              const float* __restrict__ dinv,
                                              const __half* __restrict__ h1,
                                              const float* __restrict__ b1,
                                              const float* __restrict__ W2,
                                              __half2* __restrict__ h2, int n) {
    int lane = threadIdx.x & 15;
    int i = (blockIdx.x * 256 + threadIdx.x) >> 4;
    if (i >= n) return;
    unsigned e0 = row_ptr[i], e1 = row_ptr[i + 1];
    float acc = 0.f;
    unsigned e = e0;
    for (; e + 8 <= e1; e += 8) {
        int s0 = adj[e + 0], s1 = adj[e + 1], s2 = adj[e + 2], s3 = adj[e + 3];
        int s4 = adj[e + 4], s5 = adj[e + 5], s6 = adj[e + 6], s7 = adj[e + 7];
        float v0 = __half2float(h1[(size_t)s0 * F_HID + lane]);
        float v1 = __half2float(h1[(size_t)s1 * F_HID + lane]);
        float v2 = __half2float(h1[(size_t)s2 * F_HID + lane]);
        float v3 = __half2float(h1[(size_t)s3 * F_HID + lane]);
        float v4 = __half2float(h1[(size_t)s4 * F_HID + lane]);
        float v5 = __half2float(h1[(size_t)s5 * F_HID + lane]);
        float v6 = __half2float(h1[(size_t)s6 * F_HID + lane]);
        float v7 = __half2float(h1[(size_t)s7 * F_HID + lane]);
        acc += ((v0 + v1) + (v2 + v3)) + ((v4 + v5) + (v6 + v7));
    }
    for (; e + 4 <= e1; e += 4) {
        int s0 = adj[e + 0], s1 = adj[e + 1], s2 = adj[e + 2], s3 = adj[e + 3];
        float v0 = __half2float(h1[(size_t)s0 * F_HID + lane]);
        float v1 = __half2float(h1[(size_t)s1 * F_HID + lane]);
        float v2 = __half2float(h1[(size_t)s2 * F_HID + lane]);
        float v3 = __half2float(h1[(size_t)s3 * F_HID + lane]);
        acc += (v0 + v1) + (v2 + v3);
    }
    for (; e < e1; e++)
        acc += __half2float(h1[(size_t)adj[e] * F_HID + lane]);
    float di = dinv[i];
    // (sum_s h1'[s] + h1'[i]) * di + b1
    acc = (acc + __half2float(h1[(size_t)i * F_HID + lane])) * di + b1[lane];
    float v = fmaxf(acc, 0.f);
    float c0 = v * W2[lane * 2 + 0];
    float c1 = v * W2[lane * 2 + 1];
#pragma unroll
    for (int off = 1; off < 16; off <<= 1) {
        c0 += __shfl_xor(c0, off, 64);
        c1 += __shfl_xor(c1, off, 64);
    }
    // h2' = fp16(dinv * h2): 4B/node -> 2 MB total, L2-resident per XCD for agg2
    if (lane == 0) h2[i] = __floats2half2_rn(c0 * di, c1 * di);
}

// ---- layer-2 aggregate + self-loop + bias + log_softmax -> out ----
// h2 is fp16 (2 MB working set, fits each XCD's 4 MB L2): per edge adj + 4B row.
__global__ __launch_bounds__(256) void k_agg2(const int* __restrict__ adj,
                                              const unsigned* __restrict__ row_ptr,
                                              const float* __restrict__ dinv,
                                              const __half2* __restrict__ h2,
                                              const float* __restrict__ b2,
                                              float2* __restrict__ out, int n) {
    int lane = threadIdx.x & 15;
    int i = (blockIdx.x * 256 + threadIdx.x) >> 4;
    if (i >= n) return;
    unsigned e0 = row_ptr[i], e1 = row_ptr[i + 1];
    float a0 = 0.f, a1 = 0.f;
    for (unsigned e = e0 + lane; e < e1; e += 16) {
        float2 hv = __half22float2(h2[adj[e]]);
        a0 += hv.x;
        a1 += hv.y;
    }
#pragma unroll
    for (int off = 1; off < 16; off <<= 1) {
        a0 += __shfl_xor(a0, off, 64);
        a1 += __shfl_xor(a1, off, 64);
    }
    if (lane == 0) {
        float di = dinv[i];
        float2 hs = __half22float2(h2[i]);
        float v0 = (a0 + hs.x) * di + b2[0];
        float v1 = (a1 + hs.y) * di + b2[1];
        float m = fmaxf(v0, v1);
        float lse = m + log1pf(expf(fminf(v0, v1) - m));
        out[i] = make_float2(v0 - lse, v1 - lse);
    }
}

extern "C" void kernel_launch(void* const* d_in, const int* in_sizes, int n_in,
                              void* d_out, int out_size, void* d_ws, size_t ws_size,
                              hipStream_t stream) {
    const float* x  = (const float*)d_in[0];
    const int*   ei = (const int*)d_in[1];
    const float* W1 = (const float*)d_in[2];
    const float* b1 = (const float*)d_in[3];
    const float* W2 = (const float*)d_in[4];
    const float* b2 = (const float*)d_in[5];

    int n = in_sizes[0] / F_IN;   // 500000
    int E = in_sizes[1] / 2;      // 8000000
    const int* src = ei;
    const int* dst = ei + E;
    int B = (n + NPB - 1) / NPB;  // 245 buckets

    // workspace layout (all 64B-aligned); binned overlays h1 (binned dead before gemm1)
    char* ws = (char*)d_ws;
    size_t off = 0;
    auto alloc = [&](size_t bytes) { char* p = ws + off; off = (off + bytes + 63) & ~size_t(63); return p; };
    float*    dinv    = (float*)alloc(4 * (size_t)n);
    unsigned* row_ptr = (unsigned*)alloc(4 * ((size_t)n + 1));
    unsigned* bcnt    = (unsigned*)alloc(1024);
    unsigned* bbase   = (unsigned*)alloc(1028);
    unsigned* bfill   = (unsigned*)alloc(1024);
    char*     regionA = alloc(32000000);          // binned (4E=32MB) then h1 fp16 (32n=16MB)
    unsigned* binned  = (unsigned*)regionA;
    __half*   h1      = (__half*)regionA;
    int*      adj     = (int*)alloc(4 * (size_t)E);
    __half2*  h2      = (__half2*)alloc(4 * (size_t)n);    // 2 MB, fp16

    int bN = (n + 255) / 256;
    int bBIN = (E + 8191) / 8192;
    int bG = (n * 16 + 255) / 256;

    hipMemsetAsync(bcnt, 0, 1024, stream);
    k_hist1 <<<1024, 256, 0, stream>>>(dst, bcnt, E);
    k_scanb <<<1, 256, 0, stream>>>(bcnt, bbase, bfill, row_ptr, n, E);
    k_bin   <<<bBIN, 1024, 0, stream>>>(src, dst, bfill, binned, E);
    k_bucket<<<B, 1024, 0, stream>>>(binned, bbase, adj, row_ptr, dinv, n);
    k_gemm1 <<<bN, 256, 0, stream>>>(x, W1, dinv, h1, n);
    k_agg1  <<<bG, 256, 0, stream>>>(adj, row_ptr, dinv, h1, b1, W2, h2, n);
    k_agg2  <<<bG, 256, 0, stream>>>(adj, row_ptr, dinv, h2, b2, (float2*)d_out, n);
}

// Round 8
// 723.778 us; speedup vs baseline: 1.7225x; 1.0280x over previous
//
#include <hip/hip_runtime.h>
#include <hip/hip_fp16.h>

#define F_IN   128
#define F_HID  16
#define NPB    2048          // nodes per bucket
#define NPB_SH 11
#define SRC_BITS 19
#define SRC_MASK 0x7FFFFu
#define BIN_EPB 8192         // edges per k_bin block

// ---------------- bucket histogram (dst >> 11) ----------------
__global__ __launch_bounds__(256) void k_hist1(const int* __restrict__ dst,
                                               unsigned* __restrict__ bcnt, int E) {
    __shared__ unsigned h[256];
    h[threadIdx.x] = 0;
    __syncthreads();
    for (int i = blockIdx.x * 256 + threadIdx.x; i < E; i += gridDim.x * 256)
        atomicAdd(&h[((unsigned)dst[i]) >> NPB_SH], 1u);
    __syncthreads();
    if (h[threadIdx.x]) atomicAdd(&bcnt[threadIdx.x], h[threadIdx.x]);
}

// ---------------- scan 256 bucket counts ----------------
__global__ __launch_bounds__(256) void k_scanb(const unsigned* __restrict__ bcnt,
                                               unsigned* __restrict__ bbase,
                                               unsigned* __restrict__ bfill,
                                               unsigned* __restrict__ row_ptr,
                                               int n, int E) {
    __shared__ unsigned s[256];
    unsigned v = bcnt[threadIdx.x];
    s[threadIdx.x] = v;
    __syncthreads();
    for (int off = 1; off < 256; off <<= 1) {
        unsigned t = (threadIdx.x >= (unsigned)off) ? s[threadIdx.x - off] : 0u;
        __syncthreads();
        s[threadIdx.x] += t;
        __syncthreads();
    }
    unsigned incl = s[threadIdx.x];
    bbase[threadIdx.x + 1] = incl;
    bfill[threadIdx.x] = incl - v;    // exclusive
    if (threadIdx.x == 0) { bbase[0] = 0; row_ptr[n] = (unsigned)E; }
}

// ---------------- bin edges into buckets (LDS-reorder radix partition) ----------------
// Old version did 8M random 4B global stores (each binned line assembled by ~32
// different blocks across all XCDs -> per-store line RMW). New version sorts the
// block's 8192 edges by bucket in LDS first, then writes each bucket's run
// contiguously: a wave's stores form ~2 coherent segments instead of 64 random
// lines. Output layout identical (same bfill reservation).
__global__ __launch_bounds__(1024) void k_bin(const int* __restrict__ src,
                                              const int* __restrict__ dst,
                                              unsigned* __restrict__ bfill,
                                              unsigned* __restrict__ binned, int E) {
    __shared__ unsigned hist[256], lbase[256], runbase[256], fill2[256], ssc[256];
    __shared__ unsigned stage[BIN_EPB];          // 32 KB bucket-sorted vals
    __shared__ unsigned char abkt[BIN_EPB];      // 8 KB bucket tag per stage slot
    int t = threadIdx.x;
    if (t < 256) { hist[t] = 0; fill2[t] = 0; }
    __syncthreads();
    unsigned val[8]; unsigned bkt[8]; bool ok[8];
    int base = blockIdx.x * BIN_EPB;
#pragma unroll
    for (int k = 0; k < 8; k++) {
        int e = base + k * 1024 + t;
        ok[k] = e < E;
        if (ok[k]) {
            unsigned d = (unsigned)dst[e];
            unsigned s = (unsigned)src[e];
            bkt[k] = d >> NPB_SH;
            val[k] = ((d & (NPB - 1)) << SRC_BITS) | s;
            atomicAdd(&hist[bkt[k]], 1u);
        }
    }
    __syncthreads();
    // block-local exclusive scan of hist (Hillis-Steele over 256)
    if (t < 256) ssc[t] = hist[t];
    __syncthreads();
    for (int off = 1; off < 256; off <<= 1) {
        unsigned v2 = 0;
        if (t < 256 && t >= off) v2 = ssc[t - off];
        __syncthreads();
        if (t < 256) ssc[t] += v2;
        __syncthreads();
    }
    if (t < 256) lbase[t] = ssc[t] - hist[t];
    // reserve this block's global run per bucket
    if (t < 256 && hist[t]) runbase[t] = atomicAdd(&bfill[t], hist[t]);
    __syncthreads();
    // scatter into LDS, bucket-sorted
#pragma unroll
    for (int k = 0; k < 8; k++) {
        if (ok[k]) {
            unsigned p = lbase[bkt[k]] + atomicAdd(&fill2[bkt[k]], 1u);
            stage[p] = val[k];
            abkt[p] = (unsigned char)bkt[k];
        }
    }
    __syncthreads();
    // sequential copy-out: consecutive p -> consecutive global within each run
    int tot = E - base; if (tot > BIN_EPB) tot = BIN_EPB;
    for (int p = t; p < tot; p += 1024) {
        unsigned b = abkt[p];
        binned[runbase[b] + (p - lbase[b])] = stage[p];
    }
}

// ---- per-bucket: node histogram -> row_ptr, dinv, place adj (LDS atomics only) ----
__global__ __launch_bounds__(1024) void k_bucket(const unsigned* __restrict__ binned,
                                                 const unsigned* __restrict__ bbase,
                                                 int* __restrict__ adj,
                                                 unsigned* __restrict__ row_ptr,
                                                 float* __restrict__ dinv,
                                                 int n) {
    __shared__ unsigned cnt[NPB];
    __shared__ unsigned base[NPB];
    __shared__ unsigned pairs[1024];
    int b = blockIdx.x;
    unsigned estart = bbase[b], eend = bbase[b + 1];
    unsigned ecount = eend - estart;
    int nb_base = b * NPB;
    cnt[threadIdx.x] = 0; cnt[threadIdx.x + 1024] = 0;
    __syncthreads();
    for (unsigned i = threadIdx.x; i < ecount; i += 1024)
        atomicAdd(&cnt[binned[estart + i] >> SRC_BITS], 1u);
    __syncthreads();
    // scan 2048 counters: pair-sum + Hillis-Steele over 1024
    unsigned c0 = cnt[2 * threadIdx.x], c1 = cnt[2 * threadIdx.x + 1];
    pairs[threadIdx.x] = c0 + c1;
    __syncthreads();
    for (int off = 1; off < 1024; off <<= 1) {
        unsigned t = (threadIdx.x >= (unsigned)off) ? pairs[threadIdx.x - off] : 0u;
        __syncthreads();
        pairs[threadIdx.x] += t;
        __syncthreads();
    }
    unsigned ip = pairs[threadIdx.x];
    unsigned e0 = ip - c0 - c1;         // exclusive offset of node 2t
    unsigned e1 = ip - c1;              // exclusive offset of node 2t+1
    base[2 * threadIdx.x] = e0;
    base[2 * threadIdx.x + 1] = e1;
    int g0 = nb_base + 2 * threadIdx.x, g1 = g0 + 1;
    if (g0 < n) { row_ptr[g0] = estart + e0; dinv[g0] = rsqrtf((float)c0 + 1.0f); }
    if (g1 < n) { row_ptr[g1] = estart + e1; dinv[g1] = rsqrtf((float)c1 + 1.0f); }
    __syncthreads();
    cnt[threadIdx.x] = 0; cnt[threadIdx.x + 1024] = 0;   // reuse as fill
    __syncthreads();
    for (unsigned i = threadIdx.x; i < ecount; i += 1024) {
        unsigned v = binned[estart + i];
        unsigned ldst = v >> SRC_BITS;
        unsigned pos = base[ldst] + atomicAdd(&cnt[ldst], 1u);
        adj[estart + pos] = (int)(v & SRC_MASK);
    }
}

// ---------------- h1' = fp16( dinv .* (x @ W1) )  (LDS-staged + reg dbuf) ----------------
#define KC 32
#define XS_STRIDE 36
__global__ __launch_bounds__(256) void k_gemm1(const float* __restrict__ x,
                                               const float* __restrict__ W1,
                                               const float* __restrict__ dinv,
                                               __half* __restrict__ h1, int n) {
    __shared__ float Ws[F_IN * F_HID];          // 8 KB
    __shared__ float xs[256 * XS_STRIDE];       // 36 KB
    for (int i = threadIdx.x; i < F_IN * F_HID; i += 256) Ws[i] = W1[i];
    int t = threadIdx.x;
    int node0 = blockIdx.x * 256;
    bool active = (node0 + t) < n;
    float acc[F_HID];
#pragma unroll
    for (int c = 0; c < F_HID; c++) acc[c] = 0.f;

    float4 rbuf[8];
    auto loadc = [&](int c) {
#pragma unroll
        for (int i2 = 0; i2 < 8; i2++) {
            int f = t + i2 * 256;                // float4 index 0..2047
            int r = f >> 3;                      // staged row 0..255
            int j4 = f & 7;                      // float4 within chunk
            int gn = node0 + r;
            rbuf[i2] = (gn < n)
                ? *(const float4*)(x + (size_t)gn * F_IN + c * KC + j4 * 4)
                : make_float4(0.f, 0.f, 0.f, 0.f);
        }
    };
    loadc(0);
    for (int c = 0; c < F_IN / KC; c++) {       // 4 K-chunks
        __syncthreads();                         // xs free to overwrite (orders Ws on c==0)
#pragma unroll
        for (int i2 = 0; i2 < 8; i2++) {
            int f = t + i2 * 256;
            int r = f >> 3;
            int j4 = f & 7;
            *(float4*)(xs + r * XS_STRIDE + j4 * 4) = rbuf[i2];
        }
        __syncthreads();                         // xs ready
        if (c + 1 < F_IN / KC) loadc(c + 1);     // in-flight during compute below
        if (active) {
#pragma unroll
            for (int j4 = 0; j4 < 8; j4++) {
                float4 p = *(const float4*)(xs + t * XS_STRIDE + j4 * 4);
                int kk = c * KC + j4 * 4;
                const float* w0 = &Ws[(kk + 0) * F_HID];
                const float* w1 = &Ws[(kk + 1) * F_HID];
                const float* w2 = &Ws[(kk + 2) * F_HID];
                const float* w3 = &Ws[(kk + 3) * F_HID];
#pragma unroll
                for (int cc = 0; cc < F_HID; cc++)
                    acc[cc] += p.x * w0[cc] + p.y * w1[cc] + p.z * w2[cc] + p.w * w3[cc];
            }
        }
    }
    if (!active) return;
    float di = dinv[node0 + t];
    __half2 hv[8];
#pragma unroll
    for (int q = 0; q < 8; q++)
        hv[q] = __floats2half2_rn(acc[2 * q] * di, acc[2 * q + 1] * di);
    uint4* out = (uint4*)(h1 + (size_t)(node0 + t) * F_HID);   // 32B/node
    out[0] = *(uint4*)&hv[0];
    out[1] = *(uint4*)&hv[4];
}

// ---- layer-1 aggregate + self-loop + bias + ReLU + GEMM2 -> h2' (fp16) ----
__global__ __launch_bounds__(256) void k_agg1(const int* __restrict__ adj,
                                              const unsigned* __restrict__ row_ptr,
                                              const float* __restrict__ dinv,
                                              const __half* __restrict__ h1,
                                              const float* __restrict__ b1,
                                              const float* __restrict__ W2,
                                              __half2* __restrict__ h2, int n) {
    int lane = threadIdx.x & 15;
    int i = (blockIdx.x * 256 + threadIdx.x) >> 4;
    if (i >= n) return;
    unsigned e0 = row_ptr[i], e1 = row_ptr[i + 1];
    float acc = 0.f;
    unsigned e = e0;
    for (; e + 8 <= e1; e += 8) {
        int s0 = adj[e + 0], s1 = adj[e + 1], s2 = adj[e + 2], s3 = adj[e + 3];
        int s4 = adj[e + 4], s5 = adj[e + 5], s6 = adj[e + 6], s7 = adj[e + 7];
        float v0 = __half2float(h1[(size_t)s0 * F_HID + lane]);
        float v1 = __half2float(h1[(size_t)s1 * F_HID + lane]);
        float v2 = __half2float(h1[(size_t)s2 * F_HID + lane]);
        float v3 = __half2float(h1[(size_t)s3 * F_HID + lane]);
        float v4 = __half2float(h1[(size_t)s4 * F_HID + lane]);
        float v5 = __half2float(h1[(size_t)s5 * F_HID + lane]);
        float v6 = __half2float(h1[(size_t)s6 * F_HID + lane]);
        float v7 = __half2float(h1[(size_t)s7 * F_HID + lane]);
        acc += ((v0 + v1) + (v2 + v3)) + ((v4 + v5) + (v6 + v7));
    }
    for (; e + 4 <= e1; e += 4) {
        int s0 = adj[e + 0], s1 = adj[e + 1], s2 = adj[e + 2], s3 = adj[e + 3];
        float v0 = __half2float(h1[(size_t)s0 * F_HID + lane]);
        float v1 = __half2float(h1[(size_t)s1 * F_HID + lane]);
        float v2 = __half2float(h1[(size_t)s2 * F_HID + lane]);
        float v3 = __half2float(h1[(size_t)s3 * F_HID + lane]);
        acc += (v0 + v1) + (v2 + v3);
    }
    for (; e < e1; e++)
        acc += __half2float(h1[(size_t)adj[e] * F_HID + lane]);
    float di = dinv[i];
    acc = (acc + __half2float(h1[(size_t)i * F_HID + lane])) * di + b1[lane];
    float v = fmaxf(acc, 0.f);
    float c0 = v * W2[lane * 2 + 0];
    float c1 = v * W2[lane * 2 + 1];
#pragma unroll
    for (int off = 1; off < 16; off <<= 1) {
        c0 += __shfl_xor(c0, off, 64);
        c1 += __shfl_xor(c1, off, 64);
    }
    if (lane == 0) h2[i] = __floats2half2_rn(c0 * di, c1 * di);
}

// ---- layer-2 aggregate + self-loop + bias + log_softmax -> out ----
__global__ __launch_bounds__(256) void k_agg2(const int* __restrict__ adj,
                                              const unsigned* __restrict__ row_ptr,
                                              const float* __restrict__ dinv,
                                              const __half2* __restrict__ h2,
                                              const float* __restrict__ b2,
                                              float2* __restrict__ out, int n) {
    int lane = threadIdx.x & 15;
    int i = (blockIdx.x * 256 + threadIdx.x) >> 4;
    if (i >= n) return;
    unsigned e0 = row_ptr[i], e1 = row_ptr[i + 1];
    float a0 = 0.f, a1 = 0.f;
    for (unsigned e = e0 + lane; e < e1; e += 16) {
        float2 hv = __half22float2(h2[adj[e]]);
        a0 += hv.x;
        a1 += hv.y;
    }
#pragma unroll
    for (int off = 1; off < 16; off <<= 1) {
        a0 += __shfl_xor(a0, off, 64);
        a1 += __shfl_xor(a1, off, 64);
    }
    if (lane == 0) {
        float di = dinv[i];
        float2 hs = __half22float2(h2[i]);
        float v0 = (a0 + hs.x) * di + b2[0];
        float v1 = (a1 + hs.y) * di + b2[1];
        float m = fmaxf(v0, v1);
        float lse = m + log1pf(expf(fminf(v0, v1) - m));
        out[i] = make_float2(v0 - lse, v1 - lse);
    }
}

extern "C" void kernel_launch(void* const* d_in, const int* in_sizes, int n_in,
                              void* d_out, int out_size, void* d_ws, size_t ws_size,
                              hipStream_t stream) {
    const float* x  = (const float*)d_in[0];
    const int*   ei = (const int*)d_in[1];
    const float* W1 = (const float*)d_in[2];
    const float* b1 = (const float*)d_in[3];
    const float* W2 = (const float*)d_in[4];
    const float* b2 = (const float*)d_in[5];

    int n = in_sizes[0] / F_IN;   // 500000
    int E = in_sizes[1] / 2;      // 8000000
    const int* src = ei;
    const int* dst = ei + E;
    int B = (n + NPB - 1) / NPB;  // 245 buckets

    // workspace layout (all 64B-aligned); binned overlays h1 (binned dead before gemm1)
    char* ws = (char*)d_ws;
    size_t off = 0;
    auto alloc = [&](size_t bytes) { char* p = ws + off; off = (off + bytes + 63) & ~size_t(63); return p; };
    float*    dinv    = (float*)alloc(4 * (size_t)n);
    unsigned* row_ptr = (unsigned*)alloc(4 * ((size_t)n + 1));
    unsigned* bcnt    = (unsigned*)alloc(1024);
    unsigned* bbase   = (unsigned*)alloc(1028);
    unsigned* bfill   = (unsigned*)alloc(1024);
    char*     regionA = alloc(32000000);          // binned (4E=32MB) then h1 fp16 (32n=16MB)
    unsigned* binned  = (unsigned*)regionA;
    __half*   h1      = (__half*)regionA;
    int*      adj     = (int*)alloc(4 * (size_t)E);
    __half2*  h2      = (__half2*)alloc(4 * (size_t)n);    // 2 MB, fp16

    int bN = (n + 255) / 256;
    int bBIN = (E + BIN_EPB - 1) / BIN_EPB;
    int bG = (n * 16 + 255) / 256;

    hipMemsetAsync(bcnt, 0, 1024, stream);
    k_hist1 <<<1024, 256, 0, stream>>>(dst, bcnt, E);
    k_scanb <<<1, 256, 0, stream>>>(bcnt, bbase, bfill, row_ptr, n, E);
    k_bin   <<<bBIN, 1024, 0, stream>>>(src, dst, bfill, binned, E);
    k_bucket<<<B, 1024, 0, stream>>>(binned, bbase, adj, row_ptr, dinv, n);
    k_gemm1 <<<bN, 256, 0, stream>>>(x, W1, dinv, h1, n);
    k_agg1  <<<bG, 256, 0, stream>>>(adj, row_ptr, dinv, h1, b1, W2, h2, n);
    k_agg2  <<<bG, 256, 0, stream>>>(adj, row_ptr, dinv, h2, b2, (float2*)d_out, n);
}